// Round 7
// baseline (357.442 us; speedup 1.0000x reference)
//
#include <hip/hip_runtime.h>
#include <hip/hip_bf16.h>
#include <math.h>

#define NN 8
#define CH 128
#define HH 36
#define WWI 36
#define PP 1296      // 36*36
#define DD 1156      // 34*34
#define VP 1280      // vb row pitch (shorts) — covers d-tail fragment reads
#define KC 1152      // 128*9
#define QT 81        // q tiles of 16
#define DT 5         // d superblocks of 256 (2x128 flash halves)

typedef __attribute__((ext_vector_type(8))) short short8;
typedef __attribute__((ext_vector_type(4))) float f32x4;
typedef __attribute__((ext_vector_type(8))) _Float16 half8;

__device__ inline unsigned short f2bf(float f) {
    __hip_bfloat16 h = __float2bfloat16(f);
    return __builtin_bit_cast(unsigned short, h);
}
__device__ inline float fast_tanh(float x) {
    float e = __expf(2.f * x);
    return 1.f - 2.f / (e + 1.f);
}
#define MFMA(a, b, c) __builtin_amdgcn_mfma_f32_16x16x32_bf16((a), (b), (c), 0, 0, 0)

// ---------------------------------------------------------------------------
// setup+proj merged (round 6) + zeroing of the 168 merge counters.
// ---------------------------------------------------------------------------
__global__ __launch_bounds__(256)
void k_setup(const float* __restrict__ wq, const float* __restrict__ wk,
             const float* __restrict__ wv, const float* __restrict__ wh,
             const float* __restrict__ wo, const float* __restrict__ wx,
             const float* __restrict__ c0, const float* __restrict__ w_vc,
             const float* __restrict__ b_h,
             unsigned short* __restrict__ wcat, unsigned short* __restrict__ whb,
             unsigned short* __restrict__ wob,
             float* __restrict__ hconst,
             const float* __restrict__ inp, const float* __restrict__ bx,
             unsigned short* __restrict__ xt, int* __restrict__ cnt)
{
    if (blockIdx.x >= 577) {
        // ---------------- proj path (one unit per wave) ----------------
        const int t = threadIdx.x;
        const int wave = t >> 6, lane = t & 63;
        const int pid = (blockIdx.x - 577) * 4 + wave;   // 0..1295
        const int n = pid / 162;
        const int rem = pid - n * 162;
        const int by = rem / 81;
        const int qg = rem - by * 81;
        const int quad = lane >> 4, lrow = lane & 15;
        const int p0 = qg * 16;
        const int co0 = by * 64;
        const float* in_n = inp + (size_t)n * CH * PP;
        f32x4 acc[4] = {};

#pragma unroll
        for (int ks = 0; ks < 4; ++ks) {
            union { short8 v; unsigned short u[8]; } a;
            int ci0 = ks * 32 + quad * 8;
#pragma unroll
            for (int j = 0; j < 8; ++j)
                a.u[j] = f2bf(in_n[(size_t)(ci0 + j) * PP + p0 + lrow]);
#pragma unroll
            for (int ni = 0; ni < 4; ++ni) {
                const float* wrow = wx + (size_t)(co0 + ni * 16 + lrow) * CH + ks * 32 + quad * 8;
                float4 f0 = *(const float4*)wrow;
                float4 f1 = *(const float4*)(wrow + 4);
                union { short8 v; unsigned short u[8]; } b;
                b.u[0] = f2bf(f0.x); b.u[1] = f2bf(f0.y);
                b.u[2] = f2bf(f0.z); b.u[3] = f2bf(f0.w);
                b.u[4] = f2bf(f1.x); b.u[5] = f2bf(f1.y);
                b.u[6] = f2bf(f1.z); b.u[7] = f2bf(f1.w);
                acc[ni] = MFMA(a.v, b.v, acc[ni]);
            }
        }
        unsigned short* xn = xt + (size_t)n * PP * CH;
#pragma unroll
        for (int ni = 0; ni < 4; ++ni) {
            float bv = bx[co0 + ni * 16 + lrow];
#pragma unroll
            for (int r = 0; r < 4; ++r)
                xn[(size_t)(p0 + quad * 4 + r) * CH + co0 + ni * 16 + lrow] = f2bf(acc[ni][r] + bv);
        }
        return;
    }
    if (blockIdx.x == 576) {
        __shared__ float c0s[CH];
        __shared__ float part[256];
        __shared__ float vcs[CH];
        const int t = threadIdx.x;
        const int c = t & 127, half = t >> 7;
        if (t < CH) c0s[t] = c0[t];
        __syncthreads();
        {
            const float* row = w_vc + (size_t)c * 1152 + half * 576;
            float s = 0.f;
#pragma unroll 4
            for (int j4 = 0; j4 < 144; ++j4) {
                float4 v = ((const float4*)row)[j4];
                int j = half * 576 + j4 * 4;
                s += v.x * c0s[j / 9] + v.y * c0s[(j + 1) / 9]
                   + v.z * c0s[(j + 2) / 9] + v.w * c0s[(j + 3) / 9];
            }
            part[t] = s;
        }
        __syncthreads();
        if (t < CH) vcs[t] = part[t] + part[t + 128];
        __syncthreads();
        {
            const float* wrow = wh + (size_t)c * 384 + 256 + half * 64;
            float hs = 0.f;
#pragma unroll
            for (int j4 = 0; j4 < 16; ++j4) {
                float4 v = ((const float4*)wrow)[j4];
                int ci = half * 64 + j4 * 4;
                hs += v.x * vcs[ci] + v.y * vcs[ci + 1] + v.z * vcs[ci + 2] + v.w * vcs[ci + 3];
            }
            part[t] = hs;
        }
        __syncthreads();
        if (t < CH) hconst[t] = b_h[t] + part[t] + part[t + 128];
        return;
    }
    if (blockIdx.x == 0 && threadIdx.x < 168) cnt[threadIdx.x] = 0;
    int t = blockIdx.x * 256 + threadIdx.x;    // 0..147455
    int co = t / KC;
    int rem = t - co * KC;
    int tap = rem >> 7, ci = rem & 127;
    int iidx = co * KC + ci * 9 + tap;
    wcat[t] = f2bf(wq[iidx]);
    wcat[147456 + t] = f2bf(wk[iidx]);
    wcat[294912 + t] = f2bf(wv[iidx]);
    if (t < 32768) {
        int c2 = t >> 8, k2 = t & 255;
        whb[t] = f2bf(wh[c2 * 384 + k2]);
    }
    if (t < 16384) wob[t] = f2bf(wo[t]);
}

// ---------------------------------------------------------------------------
// fused q/k/v conv — unchanged (round-1 structure; best measured).
// ---------------------------------------------------------------------------
__global__ __launch_bounds__(256)
void k_conv(const unsigned short* __restrict__ xt, const unsigned short* __restrict__ wcat,
            unsigned short* __restrict__ qt, unsigned short* __restrict__ kt,
            unsigned short* __restrict__ vb)
{
    __shared__ unsigned short lA[2][64 * 40];     // 2 x 5120 B
    __shared__ unsigned short lB[2][128 * 40];    // 2 x 10240 B
    const int t = threadIdx.x;
    const int wave = t >> 6, lane = t & 63;
    const int quad = lane >> 4, lrow = lane & 15;
    const int mode = blockIdx.y;
    const int n = blockIdx.z;
    const int limit = (mode == 0) ? PP : DD;
    const int tile0 = blockIdx.x * 64;
    if (tile0 >= limit) return;
    const unsigned short* xn = xt + (size_t)n * PP * CH;
    const unsigned short* wb = wcat + (size_t)mode * 128 * KC;

    const int arow = t >> 2, aseg = t & 3;
    int apr, apc;
    {
        int tok = tile0 + arow; if (tok >= limit) tok = limit - 1;
        int dv = (mode == 0) ? 36 : 34;
        apr = tok / dv; apc = tok - apr * dv;
    }

    uint4 ra, rb0, rb1;
    auto loadChunk = [&](int ks) {
        int tap = ks >> 2;
        int ky = tap / 3, kx = tap - ky * 3;
        int ci = (ks & 3) * 32 + aseg * 8;
        if (mode == 0) {
            int yy = apr + ky - 1, xx = apc + kx - 1;
            bool ok = (yy >= 0) && (yy < HH) && (xx >= 0) && (xx < WWI);
            ra = make_uint4(0, 0, 0, 0);
            if (ok) ra = *(const uint4*)&xn[(size_t)(yy * WWI + xx) * CH + ci];
        } else {
            int yy = apr + ky, xx = apc + kx;
            ra = *(const uint4*)&xn[(size_t)(yy * WWI + xx) * CH + ci];
        }
        rb0 = *(const uint4*)&wb[(size_t)arow * KC + ks * 32 + aseg * 8];
        rb1 = *(const uint4*)&wb[(size_t)(arow + 64) * KC + ks * 32 + aseg * 8];
    };
    auto storeChunk = [&](int buf) {
        *(uint4*)&lA[buf][arow * 40 + aseg * 8] = ra;
        *(uint4*)&lB[buf][arow * 40 + aseg * 8] = rb0;
        *(uint4*)&lB[buf][(arow + 64) * 40 + aseg * 8] = rb1;
    };

    f32x4 acc[4][2] = {};
    loadChunk(0);
    storeChunk(0);
    __syncthreads();

#pragma unroll
    for (int ks = 0; ks < 36; ++ks) {
        const int buf = ks & 1;
        if (ks < 35) loadChunk(ks + 1);
        short8 b0 = *(const short8*)&lB[buf][((wave * 2) * 16 + lrow) * 40 + quad * 8];
        short8 b1 = *(const short8*)&lB[buf][((wave * 2 + 1) * 16 + lrow) * 40 + quad * 8];
#pragma unroll
        for (int mi = 0; mi < 4; ++mi) {
            short8 a = *(const short8*)&lA[buf][(mi * 16 + lrow) * 40 + quad * 8];
            acc[mi][0] = MFMA(a, b0, acc[mi][0]);
            acc[mi][1] = MFMA(a, b1, acc[mi][1]);
        }
        if (ks < 35) storeChunk(buf ^ 1);
        __syncthreads();
    }

    if (mode == 0) {
        unsigned short* qn = qt + (size_t)n * PP * CH;
#pragma unroll
        for (int mi = 0; mi < 4; ++mi)
#pragma unroll
            for (int r = 0; r < 4; ++r) {
                int p = tile0 + mi * 16 + quad * 4 + r;
                if (p < PP)
#pragma unroll
                    for (int ni = 0; ni < 2; ++ni)
                        qn[(size_t)p * CH + (wave * 2 + ni) * 16 + lrow] = f2bf(acc[mi][ni][r]);
            }
    } else if (mode == 1) {
        unsigned short* kn = kt + (size_t)n * DD * CH;
#pragma unroll
        for (int mi = 0; mi < 4; ++mi)
#pragma unroll
            for (int r = 0; r < 4; ++r) {
                int d = tile0 + mi * 16 + quad * 4 + r;
                if (d < DD)
#pragma unroll
                    for (int ni = 0; ni < 2; ++ni)
                        kn[(size_t)d * CH + (wave * 2 + ni) * 16 + lrow] = f2bf(acc[mi][ni][r]);
            }
    } else {
        unsigned short* vn = vb + (size_t)n * CH * VP;
#pragma unroll
        for (int mi = 0; mi < 4; ++mi)
#pragma unroll
            for (int r = 0; r < 4; ++r) {
                int d = tile0 + mi * 16 + quad * 4 + r;
                if (d < DD)
#pragma unroll
                    for (int ni = 0; ni < 2; ++ni)
                        vn[(size_t)((wave * 2 + ni) * 16 + lrow) * VP + d] = f2bf(acc[mi][ni][r]);
            }
    }
}

// ---------------------------------------------------------------------------
// partial attention (round-1 structure, unchanged math) + ATOMIC TAIL MERGE:
// after writing po/pm/pl, each block threadfences and bumps a per-(n,qg)
// counter; the block seeing old==DT-1 (all 5 d-partials complete+visible)
// runs the former k_ahout in-place, one qti per wave. LDS reused exactly
// (la0 -> lp[wave], lh -> lS region), so attn occupancy is unchanged.
// ---------------------------------------------------------------------------
__global__ __launch_bounds__(256)
void k_attn(const unsigned short* __restrict__ qt, const unsigned short* __restrict__ kt,
            const unsigned short* __restrict__ vb, _Float16* __restrict__ po,
            float* __restrict__ pm, float* __restrict__ pl,
            const unsigned short* __restrict__ xt, const unsigned short* __restrict__ whb,
            const float* __restrict__ hconst, const unsigned short* __restrict__ wob,
            const float* __restrict__ bo, float* __restrict__ out,
            int* __restrict__ cnt)
{
    __shared__ unsigned short lS[2][128 * 40];    // 2 x 10240 B chunk staging
    __shared__ unsigned short lp[4][16 * 136];    // per-wave P transpose / la0
    __shared__ int mflag;
    const int t = threadIdx.x;
    const int wave = t >> 6, lane = t & 63;
    const int quad = lane >> 4, lrow = lane & 15;
    const int qg = blockIdx.x;
    const int dt = blockIdx.y;                    // 0..4
    const int n = blockIdx.z;
    const int qti = qg * 4 + wave;                // may be >= QT (tail)
    const int d0 = dt * 256;
    const unsigned short* qn = qt + (size_t)n * PP * CH;
    const unsigned short* kn = kt + (size_t)n * DD * CH;
    const unsigned short* vn = vb + (size_t)n * CH * VP;

    const int arow = t >> 2, aseg8 = (t & 3) * 8;
    const int lo0 = arow * 40 + aseg8;
    const int lo1 = (arow + 64) * 40 + aseg8;

    short8 qa[4];
    {
        int qrow = qti * 16 + lrow; if (qrow >= PP) qrow = PP - 1;
#pragma unroll
        for (int ks = 0; ks < 4; ++ks)
            qa[ks] = *(const short8*)&qn[(size_t)qrow * CH + ks * 32 + quad * 8];
    }

    f32x4 o[8] = {};
    float mx[4] = {-1e30f, -1e30f, -1e30f, -1e30f};
    float rs[4] = {0.f, 0.f, 0.f, 0.f};

#pragma unroll
    for (int h = 0; h < 2; ++h) {
        const int dbase = d0 + h * 128;
        int kr0 = dbase + arow;      if (kr0 >= DD) kr0 = DD - 1;
        int kr1 = dbase + arow + 64; if (kr1 >= DD) kr1 = DD - 1;
        const unsigned short* kp0 = kn + (size_t)kr0 * CH + aseg8;
        const unsigned short* kp1 = kn + (size_t)kr1 * CH + aseg8;
        const unsigned short* vp0 = vn + (size_t)arow * VP + dbase + aseg8;
        const unsigned short* vp1 = vn + (size_t)(arow + 64) * VP + dbase + aseg8;

        // ---- S = Q.K^T for this half, chunked over c, double-buffered ----
        f32x4 s[8] = {};
        uint4 r0 = *(const uint4*)kp0;
        uint4 r1 = *(const uint4*)kp1;
        *(uint4*)&lS[0][lo0] = r0;
        *(uint4*)&lS[0][lo1] = r1;
        __syncthreads();
#pragma unroll
        for (int ks = 0; ks < 4; ++ks) {
            const int buf = ks & 1;
            if (ks < 3) {
                r0 = *(const uint4*)(kp0 + (ks + 1) * 32);
                r1 = *(const uint4*)(kp1 + (ks + 1) * 32);
            }
#pragma unroll
            for (int ni = 0; ni < 8; ++ni) {
                short8 b = *(const short8*)&lS[buf][(ni * 16 + lrow) * 40 + quad * 8];
                s[ni] = MFMA(qa[ks], b, s[ni]);
            }
            if (ks < 3) {
                *(uint4*)&lS[buf ^ 1][lo0] = r0;
                *(uint4*)&lS[buf ^ 1][lo1] = r1;
            }
            __syncthreads();
        }

        // ---- tail mask + online-softmax combine (per wave) ----
#pragma unroll
        for (int ni = 0; ni < 8; ++ni)
            if (dbase + ni * 16 + lrow >= DD)
#pragma unroll
                for (int r = 0; r < 4; ++r) s[ni][r] = -1e30f;

        float hm[4] = {-1e30f, -1e30f, -1e30f, -1e30f};
#pragma unroll
        for (int ni = 0; ni < 8; ++ni)
#pragma unroll
            for (int r = 0; r < 4; ++r) hm[r] = fmaxf(hm[r], s[ni][r]);
#pragma unroll
        for (int off = 1; off < 16; off <<= 1)
#pragma unroll
            for (int r = 0; r < 4; ++r) hm[r] = fmaxf(hm[r], __shfl_xor(hm[r], off, 64));

        float m[4], sc[4];
#pragma unroll
        for (int r = 0; r < 4; ++r) {
            m[r] = fmaxf(mx[r], hm[r]);
            sc[r] = __expf(mx[r] - m[r]);   // h=0: exp(-1e30 - finite) = 0
        }

        float hs[4] = {0.f, 0.f, 0.f, 0.f};
#pragma unroll
        for (int ni = 0; ni < 8; ++ni)
#pragma unroll
            for (int r = 0; r < 4; ++r) {
                float e = __expf(s[ni][r] - m[r]);
                s[ni][r] = e;
                hs[r] += e;
            }
#pragma unroll
        for (int off = 1; off < 16; off <<= 1)
#pragma unroll
            for (int r = 0; r < 4; ++r) hs[r] += __shfl_xor(hs[r], off, 64);
#pragma unroll
        for (int r = 0; r < 4; ++r) {
            rs[r] = rs[r] * sc[r] + hs[r];
            mx[r] = m[r];
        }
        // rescale running O before accumulating this half's PV
#pragma unroll
        for (int ni = 0; ni < 8; ++ni)
#pragma unroll
            for (int r = 0; r < 4; ++r) o[ni][r] *= sc[r];

        // P -> wave-private LDS (C-layout -> A-layout transpose)
#pragma unroll
        for (int ni = 0; ni < 8; ++ni)
#pragma unroll
            for (int r = 0; r < 4; ++r)
                lp[wave][(quad * 4 + r) * 136 + ni * 16 + lrow] = f2bf(s[ni][r]);

        // ---- O += P.V for this half, chunked over d ----
        r0 = *(const uint4*)vp0;
        r1 = *(const uint4*)vp1;
        *(uint4*)&lS[0][lo0] = r0;
        *(uint4*)&lS[0][lo1] = r1;
        __syncthreads();
#pragma unroll
        for (int ks = 0; ks < 4; ++ks) {
            const int buf = ks & 1;
            if (ks < 3) {
                r0 = *(const uint4*)(vp0 + (ks + 1) * 32);
                r1 = *(const uint4*)(vp1 + (ks + 1) * 32);
            }
            short8 pa = *(const short8*)&lp[wave][lrow * 136 + ks * 32 + quad * 8];
#pragma unroll
            for (int ni = 0; ni < 8; ++ni) {
                short8 b = *(const short8*)&lS[buf][(ni * 16 + lrow) * 40 + quad * 8];
                o[ni] = MFMA(pa, b, o[ni]);
            }
            if (ks < 3) {
                *(uint4*)&lS[buf ^ 1][lo0] = r0;
                *(uint4*)&lS[buf ^ 1][lo1] = r1;
            }
            __syncthreads();
        }
    }

    if (qti < QT) {
        const int base = (n * QT + qti) * DT + dt;
        _Float16* pob = po + (size_t)base * 2048;
#pragma unroll
        for (int ni = 0; ni < 8; ++ni)
#pragma unroll
            for (int r = 0; r < 4; ++r)
                pob[(quad * 4 + r) * 128 + ni * 16 + lrow] = (_Float16)o[ni][r];
        if (lrow == 0)
#pragma unroll
            for (int r = 0; r < 4; ++r) {
                pm[base * 16 + quad * 4 + r] = mx[r];
                pl[base * 16 + quad * 4 + r] = rs[r];
            }
    }

    // ---- atomic tail: last block per (n,qg) merges + computes h/out ----
    __threadfence();
    if (t == 0) mflag = atomicAdd(&cnt[n * 21 + qg], 1);
    __syncthreads();
    if (mflag != DT - 1) return;
    __threadfence();
    if (qti >= QT) return;   // tail wave of qg=20 has no unit

    const int base2 = (n * QT + qti) * DT;
    const int row = lane >> 2;          // 0..15
    const int c0 = (lane & 3) * 32;

    // per-lane softmax-merge scalars for its row
    float mg = -1e30f;
#pragma unroll
    for (int d = 0; d < DT; ++d) mg = fmaxf(mg, pm[base2 * 16 + d * 16 + row]);
    float ls = 0.f;
    float sscv[DT];
#pragma unroll
    for (int d = 0; d < DT; ++d) {
        float e = __expf(pm[base2 * 16 + d * 16 + row] - mg);
        sscv[d] = e;
        ls += e * pl[base2 * 16 + d * 16 + row];
    }
    float inv = 1.f / ls;

    // merge 32 cols per lane (4 x half8 per d-partial) -> la0 (= lp[wave])
    float a0f[32];
#pragma unroll
    for (int j = 0; j < 32; ++j) a0f[j] = 0.f;
#pragma unroll
    for (int d = 0; d < DT; ++d) {
        const _Float16* pp = po + (size_t)(base2 + d) * 2048 + row * 128 + c0;
        float scv = sscv[d];
#pragma unroll
        for (int j4 = 0; j4 < 4; ++j4) {
            half8 v = *(const half8*)(pp + j4 * 8);
#pragma unroll
            for (int k = 0; k < 8; ++k) a0f[j4 * 8 + k] += scv * (float)v[k];
        }
    }
#pragma unroll
    for (int j = 0; j < 32; ++j)
        lp[wave][row * 136 + c0 + j] = f2bf(a0f[j] * inv);
    asm volatile("s_waitcnt lgkmcnt(0)" ::: "memory");
    __builtin_amdgcn_sched_barrier(0);

    // phase 2: h = tanh(whb.[x;a0]+hconst) -> lh -> out = wob.h + b_o
    const unsigned short* la0w = lp[wave];
    unsigned short* lhw = &lS[0][0] + wave * 2560;   // 16x136 region per wave
    const unsigned short* x0 = xt + (size_t)n * PP * CH;
    const int p0 = qti * 16;

    f32x4 acc1[8] = {};
#pragma unroll
    for (int ks = 0; ks < 8; ++ks) {
        int col = (ks & 3) * 32 + quad * 8;
        short8 a;
        if (ks < 4) a = *(const short8*)&x0[(size_t)(p0 + lrow) * CH + col];
        else        a = *(const short8*)&la0w[lrow * 136 + col];
#pragma unroll
        for (int ni = 0; ni < 8; ++ni) {
            short8 b = *(const short8*)&whb[(size_t)(ni * 16 + lrow) * 256 + ks * 32 + quad * 8];
            acc1[ni] = MFMA(a, b, acc1[ni]);
        }
    }
#pragma unroll
    for (int ni = 0; ni < 8; ++ni) {
        float hc = hconst[ni * 16 + lrow];
#pragma unroll
        for (int r = 0; r < 4; ++r)
            lhw[(quad * 4 + r) * 136 + ni * 16 + lrow] = f2bf(fast_tanh(acc1[ni][r] + hc));
    }
    asm volatile("s_waitcnt lgkmcnt(0)" ::: "memory");
    __builtin_amdgcn_sched_barrier(0);

    f32x4 acc2[8] = {};
#pragma unroll
    for (int ks = 0; ks < 4; ++ks) {
        short8 a = *(const short8*)&lhw[lrow * 136 + ks * 32 + quad * 8];
#pragma unroll
        for (int ni = 0; ni < 8; ++ni) {
            short8 b = *(const short8*)&wob[(size_t)(ni * 16 + lrow) * CH + ks * 32 + quad * 8];
            acc2[ni] = MFMA(a, b, acc2[ni]);
        }
    }
#pragma unroll
    for (int ni = 0; ni < 8; ++ni) {
        float bv = bo[ni * 16 + lrow];
#pragma unroll
        for (int r = 0; r < 4; ++r)
            out[((size_t)(n * CH + ni * 16 + lrow)) * PP + p0 + quad * 4 + r] = acc2[ni][r] + bv;
    }
}

// ---------------------------------------------------------------------------
extern "C" void kernel_launch(void* const* d_in, const int* in_sizes, int n_in,
                              void* d_out, int out_size, void* d_ws, size_t ws_size,
                              hipStream_t stream)
{
    const float* inp  = (const float*)d_in[0];
    const float* c0   = (const float*)d_in[1];
    const float* w_x  = (const float*)d_in[2];
    const float* b_x  = (const float*)d_in[3];
    const float* w_qx = (const float*)d_in[4];
    const float* w_kx = (const float*)d_in[6];
    const float* w_vx = (const float*)d_in[8];
    const float* w_vc = (const float*)d_in[9];
    const float* w_h  = (const float*)d_in[14];
    const float* b_h  = (const float*)d_in[15];
    const float* w_o  = (const float*)d_in[16];
    const float* b_o  = (const float*)d_in[17];
    float* out = (float*)d_out;

    char* w = (char*)d_ws;
    unsigned short* xt   = (unsigned short*)(w);             // 2,654,208
    unsigned short* qt   = (unsigned short*)(w + 2654208);   // 2,654,208
    unsigned short* kt   = (unsigned short*)(w + 5308416);   // 2,367,488
    unsigned short* vb   = (unsigned short*)(w + 7675904);   // 2,621,440
    unsigned short* wcat = (unsigned short*)(w + 12951552);  // 884,736
    unsigned short* whb  = (unsigned short*)(w + 13869056);  // 65,536
    unsigned short* wob  = (unsigned short*)(w + 13934592);  // 32,768
    float* hconst        = (float*)(w + 13967360);           // 512
    float* pm            = (float*)(w + 13967872);           // 207,360
    float* pl            = (float*)(w + 14382592);           // 207,360
    _Float16* po         = (_Float16*)(w + 14797312);        // 13,271,040
    int* cnt             = (int*)(w + 28068352);             // 672

    // setup blocks 0..576 + proj blocks 577..900 (independent; one launch)
    hipLaunchKernelGGL(k_setup, dim3(901), dim3(256), 0, stream,
                       w_qx, w_kx, w_vx, w_h, w_o, w_x, c0, w_vc, b_h,
                       wcat, whb, wob, hconst, inp, b_x, xt, cnt);

    hipLaunchKernelGGL(k_conv, dim3(21, 3, NN), dim3(256), 0, stream, xt, wcat, qt, kt, vb);

    hipLaunchKernelGGL(k_attn, dim3(21, DT, NN), dim3(256), 0, stream,
                       qt, kt, vb, po, pm, pl,
                       xt, whb, hconst, wob, b_o, out, cnt);
}

// Round 8
// 181.912 us; speedup vs baseline: 1.9649x; 1.9649x over previous
//
#include <hip/hip_runtime.h>
#include <hip/hip_bf16.h>
#include <math.h>

#define NN 8
#define CH 128
#define HH 36
#define WWI 36
#define PP 1296      // 36*36
#define DD 1156      // 34*34
#define VP 1280      // vb row pitch (shorts) — covers d-tail fragment reads
#define KC 1152      // 128*9
#define QT 81        // q tiles of 16
#define DT 5         // d superblocks of 256 (2x128 flash halves)
#define XPP 1444     // 38*38 padded token grid

typedef __attribute__((ext_vector_type(8))) short short8;
typedef __attribute__((ext_vector_type(4))) float f32x4;
typedef __attribute__((ext_vector_type(8))) _Float16 half8;

__device__ inline unsigned short f2bf(float f) {
    __hip_bfloat16 h = __float2bfloat16(f);
    return __builtin_bit_cast(unsigned short, h);
}
__device__ inline float fast_tanh(float x) {
    float e = __expf(2.f * x);
    return 1.f - 2.f / (e + 1.f);
}
#define MFMA(a, b, c) __builtin_amdgcn_mfma_f32_16x16x32_bf16((a), (b), (c), 0, 0, 0)
#define GLDS(g, l) __builtin_amdgcn_global_load_lds( \
    (const __attribute__((address_space(1))) unsigned int*)(g), \
    (__attribute__((address_space(3))) unsigned int*)(l), 16, 0, 0)

// ---------------------------------------------------------------------------
// setup+proj merged + xp halo-border zeroing (blocks 901..908).
// xp is the zero-padded [38][38][128] bf16 x-tensor; proj writes interior.
// ---------------------------------------------------------------------------
__global__ __launch_bounds__(256)
void k_setup(const float* __restrict__ wq, const float* __restrict__ wk,
             const float* __restrict__ wv, const float* __restrict__ wh,
             const float* __restrict__ wo, const float* __restrict__ wx,
             const float* __restrict__ c0, const float* __restrict__ w_vc,
             const float* __restrict__ b_h,
             unsigned short* __restrict__ wcat, unsigned short* __restrict__ whb,
             unsigned short* __restrict__ wob,
             float* __restrict__ hconst,
             const float* __restrict__ inp, const float* __restrict__ bx,
             unsigned short* __restrict__ xp)
{
    if (blockIdx.x >= 901) {
        // ---------------- zero the 148 halo-border cells of xp[n] ----------
        const int n = blockIdx.x - 901;
        unsigned short* xpn = xp + (size_t)n * XPP * CH;
        for (int b = threadIdx.x; b < 148 * 16; b += 256) {
            int cell = b >> 4, part = b & 15;
            int y, x;
            if (cell < 38)       { y = 0;              x = cell; }
            else if (cell < 76)  { y = 37;             x = cell - 38; }
            else if (cell < 112) { y = cell - 76 + 1;  x = 0; }
            else                 { y = cell - 112 + 1; x = 37; }
            *(uint4*)&xpn[((size_t)(y * 38 + x)) * CH + part * 8] = make_uint4(0, 0, 0, 0);
        }
        return;
    }
    if (blockIdx.x >= 577) {
        // ---------------- proj path (one unit per wave) ----------------
        const int t = threadIdx.x;
        const int wave = t >> 6, lane = t & 63;
        const int pid = (blockIdx.x - 577) * 4 + wave;   // 0..1295
        const int n = pid / 162;
        const int rem = pid - n * 162;
        const int by = rem / 81;
        const int qg = rem - by * 81;
        const int quad = lane >> 4, lrow = lane & 15;
        const int p0 = qg * 16;
        const int co0 = by * 64;
        const float* in_n = inp + (size_t)n * CH * PP;
        f32x4 acc[4] = {};

#pragma unroll
        for (int ks = 0; ks < 4; ++ks) {
            union { short8 v; unsigned short u[8]; } a;
            int ci0 = ks * 32 + quad * 8;
#pragma unroll
            for (int j = 0; j < 8; ++j)
                a.u[j] = f2bf(in_n[(size_t)(ci0 + j) * PP + p0 + lrow]);
#pragma unroll
            for (int ni = 0; ni < 4; ++ni) {
                const float* wrow = wx + (size_t)(co0 + ni * 16 + lrow) * CH + ks * 32 + quad * 8;
                float4 f0 = *(const float4*)wrow;
                float4 f1 = *(const float4*)(wrow + 4);
                union { short8 v; unsigned short u[8]; } b;
                b.u[0] = f2bf(f0.x); b.u[1] = f2bf(f0.y);
                b.u[2] = f2bf(f0.z); b.u[3] = f2bf(f0.w);
                b.u[4] = f2bf(f1.x); b.u[5] = f2bf(f1.y);
                b.u[6] = f2bf(f1.z); b.u[7] = f2bf(f1.w);
                acc[ni] = MFMA(a.v, b.v, acc[ni]);
            }
        }
        unsigned short* xn = xp + (size_t)n * XPP * CH;
#pragma unroll
        for (int ni = 0; ni < 4; ++ni) {
            float bv = bx[co0 + ni * 16 + lrow];
#pragma unroll
            for (int r = 0; r < 4; ++r) {
                int p = p0 + quad * 4 + r;
                int off = ((p / 36 + 1) * 38 + (p % 36) + 1) * CH;
                xn[(size_t)off + co0 + ni * 16 + lrow] = f2bf(acc[ni][r] + bv);
            }
        }
        return;
    }
    if (blockIdx.x == 576) {
        __shared__ float c0s[CH];
        __shared__ float part[256];
        __shared__ float vcs[CH];
        const int t = threadIdx.x;
        const int c = t & 127, half = t >> 7;
        if (t < CH) c0s[t] = c0[t];
        __syncthreads();
        {
            const float* row = w_vc + (size_t)c * 1152 + half * 576;
            float s = 0.f;
#pragma unroll 4
            for (int j4 = 0; j4 < 144; ++j4) {
                float4 v = ((const float4*)row)[j4];
                int j = half * 576 + j4 * 4;
                s += v.x * c0s[j / 9] + v.y * c0s[(j + 1) / 9]
                   + v.z * c0s[(j + 2) / 9] + v.w * c0s[(j + 3) / 9];
            }
            part[t] = s;
        }
        __syncthreads();
        if (t < CH) vcs[t] = part[t] + part[t + 128];
        __syncthreads();
        {
            const float* wrow = wh + (size_t)c * 384 + 256 + half * 64;
            float hs = 0.f;
#pragma unroll
            for (int j4 = 0; j4 < 16; ++j4) {
                float4 v = ((const float4*)wrow)[j4];
                int ci = half * 64 + j4 * 4;
                hs += v.x * vcs[ci] + v.y * vcs[ci + 1] + v.z * vcs[ci + 2] + v.w * vcs[ci + 3];
            }
            part[t] = hs;
        }
        __syncthreads();
        if (t < CH) hconst[t] = b_h[t] + part[t] + part[t + 128];
        return;
    }
    int t = blockIdx.x * 256 + threadIdx.x;    // 0..147455
    int co = t / KC;
    int rem = t - co * KC;
    int tap = rem >> 7, ci = rem & 127;
    int iidx = co * KC + ci * 9 + tap;
    wcat[t] = f2bf(wq[iidx]);
    wcat[147456 + t] = f2bf(wk[iidx]);
    wcat[294912 + t] = f2bf(wv[iidx]);
    if (t < 32768) {
        int c2 = t >> 8, k2 = t & 255;
        whb[t] = f2bf(wh[c2 * 384 + k2]);
    }
    if (t < 16384) wob[t] = f2bf(wo[t]);
}

// ---------------------------------------------------------------------------
// fused q/k/v conv — T3/T4 pipeline: global_load_lds (width 16) into a
// 3-deep LDS ring, raw s_barrier + counted vmcnt(6) (loads span barriers,
// never drained in the main loop), sched_barrier(0) pins regions (rule #18).
// Linear 64-B LDS rows: bank-slot occupancy (row&1)*4+quad is uniform
// 8 lanes/slot = minimum cycles, no swizzle needed. Halo via padded xp.
// ---------------------------------------------------------------------------
__global__ __launch_bounds__(256)
void k_conv(const unsigned short* __restrict__ xp, const unsigned short* __restrict__ wcat,
            unsigned short* __restrict__ qt, unsigned short* __restrict__ kt,
            unsigned short* __restrict__ vb)
{
    __shared__ unsigned short lA[3][2048];   // 3 x 64 rows x 32 shorts
    __shared__ unsigned short lB[3][4096];   // 3 x 128 rows x 32 shorts
    const int t = threadIdx.x;
    const int wave = t >> 6, lane = t & 63;
    const int quad = lane >> 4, lrow = lane & 15;
    const int mode = blockIdx.y;
    const int n = blockIdx.z;
    const int limit = (mode == 0) ? PP : DD;
    const int tile0 = blockIdx.x * 64;
    if (tile0 >= limit) return;
    const unsigned short* xn = xp + (size_t)n * XPP * CH;
    const unsigned short* wb = wcat + (size_t)mode * 128 * KC;

    const int aseg = t & 3;
    int apr, apc;
    {
        int tok = tile0 + (t >> 2); if (tok >= limit) tok = limit - 1;
        int dv = (mode == 0) ? 36 : 34;
        apr = tok / dv; apc = tok - apr * dv;
        if (mode != 0) { apr += 1; apc += 1; }   // mode0: (ky-1)+1 pad cancels
    }
    const unsigned short* wbr0 = wb + (size_t)(wave * 16 + (lane >> 2)) * KC + (lane & 3) * 8;
    const unsigned short* wbr1 = wb + (size_t)(64 + wave * 16 + (lane >> 2)) * KC + (lane & 3) * 8;
    const int ldsA = wave * 512;            // shorts
    const int ldsB0 = wave * 512;
    const int ldsB1 = 2048 + wave * 512;

    auto stage = [&](int ks, int buf) {
        int tap = ks >> 2;
        int ky = tap / 3, kx = tap - ky * 3;
        int ci = (ks & 3) * 32 + aseg * 8;
        const unsigned short* srcA = xn + ((size_t)((apr + ky) * 38 + apc + kx)) * CH + ci;
        int koff = tap * 128 + (ks & 3) * 32;
        GLDS(srcA, &lA[buf][ldsA]);
        GLDS(wbr0 + koff, &lB[buf][ldsB0]);
        GLDS(wbr1 + koff, &lB[buf][ldsB1]);
    };

    f32x4 acc[4][2] = {};
    stage(0, 0);
    stage(1, 1);
    stage(2, 2);

#pragma unroll
    for (int ks = 0; ks < 36; ++ks) {
        if (ks < 34)      asm volatile("s_waitcnt vmcnt(6)" ::: "memory");
        else if (ks == 34) asm volatile("s_waitcnt vmcnt(3)" ::: "memory");
        else               asm volatile("s_waitcnt vmcnt(0)" ::: "memory");
        __builtin_amdgcn_sched_barrier(0);
        __builtin_amdgcn_s_barrier();
        __builtin_amdgcn_sched_barrier(0);
        const int buf = ks % 3;
        short8 b0 = *(const short8*)&lB[buf][(wave * 32 + lrow) * 32 + quad * 8];
        short8 b1 = *(const short8*)&lB[buf][(wave * 32 + 16 + lrow) * 32 + quad * 8];
#pragma unroll
        for (int mi = 0; mi < 4; ++mi) {
            short8 a = *(const short8*)&lA[buf][(mi * 16 + lrow) * 32 + quad * 8];
            acc[mi][0] = MFMA(a, b0, acc[mi][0]);
            acc[mi][1] = MFMA(a, b1, acc[mi][1]);
        }
        __builtin_amdgcn_sched_barrier(0);
        __builtin_amdgcn_s_barrier();
        __builtin_amdgcn_sched_barrier(0);
        if (ks < 33) stage(ks + 3, buf);
    }

    if (mode == 0) {
        unsigned short* qn = qt + (size_t)n * PP * CH;
#pragma unroll
        for (int mi = 0; mi < 4; ++mi)
#pragma unroll
            for (int r = 0; r < 4; ++r) {
                int p = tile0 + mi * 16 + quad * 4 + r;
                if (p < PP)
#pragma unroll
                    for (int ni = 0; ni < 2; ++ni)
                        qn[(size_t)p * CH + (wave * 2 + ni) * 16 + lrow] = f2bf(acc[mi][ni][r]);
            }
    } else if (mode == 1) {
        unsigned short* kn = kt + (size_t)n * DD * CH;
#pragma unroll
        for (int mi = 0; mi < 4; ++mi)
#pragma unroll
            for (int r = 0; r < 4; ++r) {
                int d = tile0 + mi * 16 + quad * 4 + r;
                if (d < DD)
#pragma unroll
                    for (int ni = 0; ni < 2; ++ni)
                        kn[(size_t)d * CH + (wave * 2 + ni) * 16 + lrow] = f2bf(acc[mi][ni][r]);
            }
    } else {
        unsigned short* vn = vb + (size_t)n * CH * VP;
#pragma unroll
        for (int mi = 0; mi < 4; ++mi)
#pragma unroll
            for (int r = 0; r < 4; ++r) {
                int d = tile0 + mi * 16 + quad * 4 + r;
                if (d < DD)
#pragma unroll
                    for (int ni = 0; ni < 2; ++ni)
                        vn[(size_t)((wave * 2 + ni) * 16 + lrow) * VP + d] = f2bf(acc[mi][ni][r]);
            }
    }
}

// ---------------------------------------------------------------------------
// partial attention — exact round-6 version (best measured).
// ---------------------------------------------------------------------------
__global__ __launch_bounds__(256)
void k_attn(const unsigned short* __restrict__ qt, const unsigned short* __restrict__ kt,
            const unsigned short* __restrict__ vb, _Float16* __restrict__ po,
            float* __restrict__ pm, float* __restrict__ pl)
{
    __shared__ unsigned short lS[2][128 * 40];    // 2 x 10240 B chunk staging
    __shared__ unsigned short lp[4][16 * 136];    // per-wave P transpose
    const int t = threadIdx.x;
    const int wave = t >> 6, lane = t & 63;
    const int quad = lane >> 4, lrow = lane & 15;
    const int qg = blockIdx.x;
    const int dt = blockIdx.y;                    // 0..4
    const int n = blockIdx.z;
    const int qti = qg * 4 + wave;                // may be >= QT (tail)
    const int d0 = dt * 256;
    const unsigned short* qn = qt + (size_t)n * PP * CH;
    const unsigned short* kn = kt + (size_t)n * DD * CH;
    const unsigned short* vn = vb + (size_t)n * CH * VP;

    const int arow = t >> 2, aseg8 = (t & 3) * 8;
    const int lo0 = arow * 40 + aseg8;
    const int lo1 = (arow + 64) * 40 + aseg8;

    short8 qa[4];
    {
        int qrow = qti * 16 + lrow; if (qrow >= PP) qrow = PP - 1;
#pragma unroll
        for (int ks = 0; ks < 4; ++ks)
            qa[ks] = *(const short8*)&qn[(size_t)qrow * CH + ks * 32 + quad * 8];
    }

    f32x4 o[8] = {};
    float mx[4] = {-1e30f, -1e30f, -1e30f, -1e30f};
    float rs[4] = {0.f, 0.f, 0.f, 0.f};

#pragma unroll
    for (int h = 0; h < 2; ++h) {
        const int dbase = d0 + h * 128;
        int kr0 = dbase + arow;      if (kr0 >= DD) kr0 = DD - 1;
        int kr1 = dbase + arow + 64; if (kr1 >= DD) kr1 = DD - 1;
        const unsigned short* kp0 = kn + (size_t)kr0 * CH + aseg8;
        const unsigned short* kp1 = kn + (size_t)kr1 * CH + aseg8;
        const unsigned short* vp0 = vn + (size_t)arow * VP + dbase + aseg8;
        const unsigned short* vp1 = vn + (size_t)(arow + 64) * VP + dbase + aseg8;

        // ---- S = Q.K^T for this half, chunked over c, double-buffered ----
        f32x4 s[8] = {};
        uint4 r0 = *(const uint4*)kp0;
        uint4 r1 = *(const uint4*)kp1;
        *(uint4*)&lS[0][lo0] = r0;
        *(uint4*)&lS[0][lo1] = r1;
        __syncthreads();
#pragma unroll
        for (int ks = 0; ks < 4; ++ks) {
            const int buf = ks & 1;
            if (ks < 3) {
                r0 = *(const uint4*)(kp0 + (ks + 1) * 32);
                r1 = *(const uint4*)(kp1 + (ks + 1) * 32);
            }
#pragma unroll
            for (int ni = 0; ni < 8; ++ni) {
                short8 b = *(const short8*)&lS[buf][(ni * 16 + lrow) * 40 + quad * 8];
                s[ni] = MFMA(qa[ks], b, s[ni]);
            }
            if (ks < 3) {
                *(uint4*)&lS[buf ^ 1][lo0] = r0;
                *(uint4*)&lS[buf ^ 1][lo1] = r1;
            }
            __syncthreads();
        }

        // ---- tail mask + online-softmax combine (per wave) ----
#pragma unroll
        for (int ni = 0; ni < 8; ++ni)
            if (dbase + ni * 16 + lrow >= DD)
#pragma unroll
                for (int r = 0; r < 4; ++r) s[ni][r] = -1e30f;

        float hm[4] = {-1e30f, -1e30f, -1e30f, -1e30f};
#pragma unroll
        for (int ni = 0; ni < 8; ++ni)
#pragma unroll
            for (int r = 0; r < 4; ++r) hm[r] = fmaxf(hm[r], s[ni][r]);
#pragma unroll
        for (int off = 1; off < 16; off <<= 1)
#pragma unroll
            for (int r = 0; r < 4; ++r) hm[r] = fmaxf(hm[r], __shfl_xor(hm[r], off, 64));

        float m[4], sc[4];
#pragma unroll
        for (int r = 0; r < 4; ++r) {
            m[r] = fmaxf(mx[r], hm[r]);
            sc[r] = __expf(mx[r] - m[r]);   // h=0: exp(-1e30 - finite) = 0
        }

        float hs[4] = {0.f, 0.f, 0.f, 0.f};
#pragma unroll
        for (int ni = 0; ni < 8; ++ni)
#pragma unroll
            for (int r = 0; r < 4; ++r) {
                float e = __expf(s[ni][r] - m[r]);
                s[ni][r] = e;
                hs[r] += e;
            }
#pragma unroll
        for (int off = 1; off < 16; off <<= 1)
#pragma unroll
            for (int r = 0; r < 4; ++r) hs[r] += __shfl_xor(hs[r], off, 64);
#pragma unroll
        for (int r = 0; r < 4; ++r) {
            rs[r] = rs[r] * sc[r] + hs[r];
            mx[r] = m[r];
        }
        // rescale running O before accumulating this half's PV
#pragma unroll
        for (int ni = 0; ni < 8; ++ni)
#pragma unroll
            for (int r = 0; r < 4; ++r) o[ni][r] *= sc[r];

        // P -> wave-private LDS (C-layout -> A-layout transpose)
#pragma unroll
        for (int ni = 0; ni < 8; ++ni)
#pragma unroll
            for (int r = 0; r < 4; ++r)
                lp[wave][(quad * 4 + r) * 136 + ni * 16 + lrow] = f2bf(s[ni][r]);

        // ---- O += P.V for this half, chunked over d ----
        r0 = *(const uint4*)vp0;
        r1 = *(const uint4*)vp1;
        *(uint4*)&lS[0][lo0] = r0;
        *(uint4*)&lS[0][lo1] = r1;
        __syncthreads();
#pragma unroll
        for (int ks = 0; ks < 4; ++ks) {
            const int buf = ks & 1;
            if (ks < 3) {
                r0 = *(const uint4*)(vp0 + (ks + 1) * 32);
                r1 = *(const uint4*)(vp1 + (ks + 1) * 32);
            }
            short8 pa = *(const short8*)&lp[wave][lrow * 136 + ks * 32 + quad * 8];
#pragma unroll
            for (int ni = 0; ni < 8; ++ni) {
                short8 b = *(const short8*)&lS[buf][(ni * 16 + lrow) * 40 + quad * 8];
                o[ni] = MFMA(pa, b, o[ni]);
            }
            if (ks < 3) {
                *(uint4*)&lS[buf ^ 1][lo0] = r0;
                *(uint4*)&lS[buf ^ 1][lo1] = r1;
            }
            __syncthreads();
        }
    }

    if (qti < QT) {
        const int base = (n * QT + qti) * DT + dt;
        _Float16* pob = po + (size_t)base * 2048;
#pragma unroll
        for (int ni = 0; ni < 8; ++ni)
#pragma unroll
            for (int r = 0; r < 4; ++r)
                pob[(quad * 4 + r) * 128 + ni * 16 + lrow] = (_Float16)o[ni][r];
        if (lrow == 0)
#pragma unroll
            for (int r = 0; r < 4; ++r) {
                pm[base * 16 + quad * 4 + r] = mx[r];
                pl[base * 16 + quad * 4 + r] = rs[r];
            }
    }
}

// ---------------------------------------------------------------------------
// fused attention-reduce + h + out — round-6 version, x reads from padded xp.
// ---------------------------------------------------------------------------
__global__ __launch_bounds__(256)
void k_ahout(const _Float16* __restrict__ po, const float* __restrict__ pm,
             const float* __restrict__ pl, const unsigned short* __restrict__ xp,
             const unsigned short* __restrict__ whb, const float* __restrict__ hconst,
             const unsigned short* __restrict__ wob, const float* __restrict__ bo,
             float* __restrict__ out)
{
    __shared__ float sm[80], ssc[80], smg[16], sli[16];
    __shared__ unsigned short la0[16 * 136];
    __shared__ unsigned short lh[16 * 136];
    const int qti = blockIdx.x;
    const int n = blockIdx.y;
    const int base = (n * QT + qti) * DT;
    const int t = threadIdx.x;

    // ---- phase 1: merge the 5 d-superblock partials -> la0[16q x 128c] ----
    if (t < 80) sm[t] = pm[base * 16 + t];
    __syncthreads();
    if (t < 16) {
        float mg = -1e30f;
#pragma unroll
        for (int dt = 0; dt < DT; ++dt) mg = fmaxf(mg, sm[dt * 16 + t]);
        float ls = 0.f;
#pragma unroll
        for (int dt = 0; dt < DT; ++dt) ls += __expf(sm[dt * 16 + t] - mg) * pl[base * 16 + dt * 16 + t];
        smg[t] = mg; sli[t] = 1.f / ls;
    }
    __syncthreads();
    if (t < 80) ssc[t] = __expf(sm[t] - smg[t & 15]);
    __syncthreads();
    {
        const int row = t >> 4;              // (t*8)>>7
        const int c0 = (t & 15) * 8;
        float acc[8] = {};
#pragma unroll
        for (int dt = 0; dt < DT; ++dt) {
            half8 v = *(const half8*)&po[(size_t)(base + dt) * 2048 + t * 8];
            float scv = ssc[dt * 16 + row];
#pragma unroll
            for (int j = 0; j < 8; ++j) acc[j] += scv * (float)v[j];
        }
        float inv = sli[row];
#pragma unroll
        for (int j = 0; j < 8; ++j)
            la0[row * 136 + c0 + j] = f2bf(acc[j] * inv);
    }
    __syncthreads();

    // ---- phase 2: h = tanh(whb.[x;a0]+hconst) -> lh -> out = wob.h+b_o ----
    const int wave = t >> 6, lane = t & 63;
    const int quad = lane >> 4, lrow = lane & 15;
    const int p0 = qti * 16;
    const unsigned short* x0 = xp + (size_t)n * XPP * CH;
    const int ptok = p0 + lrow;
    const int xoff = ((ptok / 36 + 1) * 38 + (ptok % 36) + 1) * CH;

    f32x4 acc1[2] = {};
#pragma unroll
    for (int ks = 0; ks < 8; ++ks) {
        int col = (ks & 3) * 32 + quad * 8;
        short8 a;
        if (ks < 4) a = *(const short8*)&x0[(size_t)xoff + col];
        else        a = *(const short8*)&la0[lrow * 136 + col];
#pragma unroll
        for (int j = 0; j < 2; ++j) {
            int ni = wave * 2 + j;
            short8 b = *(const short8*)&whb[(size_t)(ni * 16 + lrow) * 256 + ks * 32 + quad * 8];
            acc1[j] = MFMA(a, b, acc1[j]);
        }
    }
#pragma unroll
    for (int j = 0; j < 2; ++j) {
        int ni = wave * 2 + j;
        float hc = hconst[ni * 16 + lrow];
#pragma unroll
        for (int r = 0; r < 4; ++r)
            lh[(quad * 4 + r) * 136 + ni * 16 + lrow] = f2bf(fast_tanh(acc1[j][r] + hc));
    }
    __syncthreads();

    f32x4 acc2[2] = {};
#pragma unroll
    for (int ks = 0; ks < 4; ++ks) {
        short8 a = *(const short8*)&lh[lrow * 136 + ks * 32 + quad * 8];
#pragma unroll
        for (int j = 0; j < 2; ++j) {
            int ni = wave * 2 + j;
            short8 b = *(const short8*)&wob[(size_t)(ni * 16 + lrow) * CH + ks * 32 + quad * 8];
            acc2[j] = MFMA(a, b, acc2[j]);
        }
    }
#pragma unroll
    for (int j = 0; j < 2; ++j) {
        int ni = wave * 2 + j;
        float bv = bo[ni * 16 + lrow];
#pragma unroll
        for (int r = 0; r < 4; ++r)
            out[((size_t)(n * CH + ni * 16 + lrow)) * PP + p0 + quad * 4 + r] = acc2[j][r] + bv;
    }
}

// ---------------------------------------------------------------------------
extern "C" void kernel_launch(void* const* d_in, const int* in_sizes, int n_in,
                              void* d_out, int out_size, void* d_ws, size_t ws_size,
                              hipStream_t stream)
{
    const float* inp  = (const float*)d_in[0];
    const float* c0   = (const float*)d_in[1];
    const float* w_x  = (const float*)d_in[2];
    const float* b_x  = (const float*)d_in[3];
    const float* w_qx = (const float*)d_in[4];
    const float* w_kx = (const float*)d_in[6];
    const float* w_vx = (const float*)d_in[8];
    const float* w_vc = (const float*)d_in[9];
    const float* w_h  = (const float*)d_in[14];
    const float* b_h  = (const float*)d_in[15];
    const float* w_o  = (const float*)d_in[16];
    const float* b_o  = (const float*)d_in[17];
    float* out = (float*)d_out;

    char* w = (char*)d_ws;
    unsigned short* xp   = (unsigned short*)(w);             // 2,957,312 (38*38*128*2*8)
    unsigned short* qt   = (unsigned short*)(w + 2957312);   // 2,654,208
    unsigned short* kt   = (unsigned short*)(w + 5611520);   // 2,367,488
    unsigned short* vb   = (unsigned short*)(w + 7979008);   // 2,621,440
    unsigned short* wcat = (unsigned short*)(w + 10600448);  // 884,736
    unsigned short* whb  = (unsigned short*)(w + 11485184);  // 65,536
    unsigned short* wob  = (unsigned short*)(w + 11550720);  // 32,768
    float* hconst        = (float*)(w + 11583488);           // 512
    float* pm            = (float*)(w + 11616256);           // 207,360
    float* pl            = (float*)(w + 11824128);           // 207,360
    _Float16* po         = (_Float16*)(w + 12031488);        // 13,271,040

    // setup 0..575 | hconst 576 | proj 577..900 | xp-border zero 901..908
    hipLaunchKernelGGL(k_setup, dim3(909), dim3(256), 0, stream,
                       w_qx, w_kx, w_vx, w_h, w_o, w_x, c0, w_vc, b_h,
                       wcat, whb, wob, hconst, inp, b_x, xp);

    hipLaunchKernelGGL(k_conv, dim3(21, 3, NN), dim3(256), 0, stream, xp, wcat, qt, kt, vb);

    hipLaunchKernelGGL(k_attn, dim3(21, DT, NN), dim3(256), 0, stream, qt, kt, vb, po, pm, pl);

    hipLaunchKernelGGL(k_ahout, dim3(QT, NN), dim3(256), 0, stream,
                       po, pm, pl, xp, whb, hconst, wob, b_o, out);
}